// Round 1
// baseline (337.292 us; speedup 1.0000x reference)
//
#include <hip/hip_runtime.h>
#include <cstdint>
#include <cstddef>

// YOLO NMS for batch 0 of preds (32, 84, 8400) fp32.
// Reference: conf=max(scores), cls=argmax, top_k(1024) by masked conf,
// pairwise IOU on class-offset xyxy boxes, greedy sequential suppression,
// top 300 kept rows -> (300,6) [x1,y1,x2,y2,conf,cls], rest zeros.

#define NA    8400
#define NCLS  80
#define NTOP  1024
#define NDET  300
#define CONF_T 0.25f
#define IOU_T  0.45f
#define MAXWH  7680.0f

// ws layout (bytes)
#define OFF_KEY   0        // u32[8400]  sortable key-hi (desc conf)
#define OFF_CLS   33600    // f32[8400]  class as float
#define OFF_CONF  67200    // f32[8400]  masked conf
#define OFF_SCONF 100800   // f32[1024]  sorted (top-1024) conf
#define OFF_SX1   104896
#define OFF_SY1   108992
#define OFF_SX2   113088
#define OFF_SY2   117184
#define OFF_SCLS  121280
#define OFF_SUP   125376   // u64[1024*16] suppression bitmask rows
// total ws usage: 256448 bytes

// swizzled LDS index: breaks the stride-64 (16-way) bank conflict in k_supmat
__device__ __forceinline__ int sw(int j) { return j + (j >> 6); }

// ---------------- K1: per-anchor conf / argmax / sort key ----------------
__global__ __launch_bounds__(256) void k_confcls(const float* __restrict__ pred,
                                                 unsigned int* __restrict__ key,
                                                 float* __restrict__ clsf,
                                                 float* __restrict__ conf)
{
    int a = blockIdx.x * 256 + threadIdx.x;
    if (a >= NA) return;
    const float* s = pred + 4 * NA;
    float best = s[a];          // class 0
    int bc = 0;
#pragma unroll 8
    for (int c = 1; c < NCLS; ++c) {
        float v = s[c * NA + a];
        if (v > best) { best = v; bc = c; }   // strict > == first-occurrence argmax
    }
    float m = (best > CONF_T) ? best : -1.0f; // masked_conf
    unsigned int u = __float_as_uint(m);
    unsigned int mono = u ^ ((u & 0x80000000u) ? 0xFFFFFFFFu : 0x80000000u);
    key[a]  = ~mono;            // ascending key == descending conf
    clsf[a] = (float)bc;
    conf[a] = m;
}

// ------------- K2: exact rank (top_k tie semantics) + scatter -------------
__global__ __launch_bounds__(256) void k_rank_scatter(const float* __restrict__ pred,
                                                      const unsigned int* __restrict__ key,
                                                      const float* __restrict__ clsf,
                                                      const float* __restrict__ conf,
                                                      float* __restrict__ wsf)
{
    __shared__ __align__(16) unsigned int kh[NA];
    int tid = threadIdx.x;
    for (int k = tid; k < NA; k += 256) kh[k] = key[k];
    __syncthreads();

    int a = blockIdx.x * 256 + tid;
    if (a >= NA) return;

    unsigned long long myk = (((unsigned long long)kh[a]) << 32) | (unsigned int)a;
    int rank = 0;
    const uint4* kv4 = (const uint4*)kh;
#pragma unroll 4
    for (int j4 = 0; j4 < NA / 4; ++j4) {
        uint4 kk = kv4[j4];              // uniform address -> LDS broadcast
        unsigned int j = (unsigned int)j4 * 4u;
        rank += ((((unsigned long long)kk.x) << 32) | (j + 0u)) < myk;
        rank += ((((unsigned long long)kk.y) << 32) | (j + 1u)) < myk;
        rank += ((((unsigned long long)kk.z) << 32) | (j + 2u)) < myk;
        rank += ((((unsigned long long)kk.w) << 32) | (j + 3u)) < myk;
    }
    if (rank < NTOP) {
#pragma clang fp contract(off)
        float x = pred[0 * NA + a], y = pred[1 * NA + a];
        float w = pred[2 * NA + a], h = pred[3 * NA + a];
        float hw = w * 0.5f, hh = h * 0.5f;     // xywh -> xyxy, ref op order
        wsf[OFF_SCONF / 4 + rank] = conf[a];
        wsf[OFF_SX1  / 4 + rank] = x - hw;
        wsf[OFF_SY1  / 4 + rank] = y - hh;
        wsf[OFF_SX2  / 4 + rank] = x + hw;
        wsf[OFF_SY2  / 4 + rank] = y + hh;
        wsf[OFF_SCLS / 4 + rank] = clsf[a];
    }
}

// ---------------- K3: 1024x1024 IOU -> suppression bitmask ----------------
__global__ __launch_bounds__(256) void k_supmat(const float* __restrict__ wsf,
                                                unsigned long long* __restrict__ sup)
{
#pragma clang fp contract(off)
    __shared__ float ox1[NTOP + 16], oy1[NTOP + 16];
    __shared__ float ox2[NTOP + 16], oy2[NTOP + 16];
    __shared__ float oar[NTOP + 16];
    int tid = threadIdx.x;
    for (int k = tid; k < NTOP; k += 256) {
        float cls = wsf[OFF_SCLS / 4 + k];
        float off = cls * MAXWH;                 // ref: b + c*MAX_WH
        float x1 = wsf[OFF_SX1 / 4 + k] + off;
        float y1 = wsf[OFF_SY1 / 4 + k] + off;
        float x2 = wsf[OFF_SX2 / 4 + k] + off;
        float y2 = wsf[OFF_SY2 / 4 + k] + off;
        int si = sw(k);
        ox1[si] = x1; oy1[si] = y1; ox2[si] = x2; oy2[si] = y2;
        oar[si] = (x2 - x1) * (y2 - y1);         // area from offset boxes (as ref)
    }
    __syncthreads();

    int gid = blockIdx.x * 256 + tid;            // 64 blocks x 256 = 16384
    int i = gid >> 4;                            // row
    int l = gid & 15;                            // u64 chunk
    int si = sw(i);
    float bx1 = ox1[si], by1 = oy1[si], bx2 = ox2[si], by2 = oy2[si], ba = oar[si];
    unsigned long long bits = 0ULL;
    int j0 = l << 6;
#pragma unroll 4
    for (int jj = 0; jj < 64; ++jj) {
        int j = j0 + jj;
        int sj = sw(j);
        float xx1 = fmaxf(bx1, ox1[sj]);
        float yy1 = fmaxf(by1, oy1[sj]);
        float xx2 = fminf(bx2, ox2[sj]);
        float yy2 = fminf(by2, oy2[sj]);
        float w  = fmaxf(xx2 - xx1, 0.0f);       // clip(rb-lt, 0)
        float hh = fmaxf(yy2 - yy1, 0.0f);
        float inter = w * hh;
        float denom = ba + oar[sj] - inter + 1e-7f;  // ref assoc order
        bool s = (j > i) && ((inter / denom) > IOU_T);
        bits |= ((unsigned long long)s) << jj;
    }
    sup[(size_t)i * 16 + l] = bits;
}

// -------- K4: sequential greedy suppression (1 wave) + emit top-300 --------
__global__ __launch_bounds__(512) void k_nms_out(const float* __restrict__ wsf,
                                                 const unsigned long long* __restrict__ sup,
                                                 float* __restrict__ out)
{
    __shared__ unsigned long long kc[16];
    __shared__ unsigned int pcs[16];
    int tid  = threadIdx.x;
    int lane = tid & 63;
    int wv   = tid >> 6;

    // keep0 = sorted_conf > CONF_T, as 16 u64 chunks via per-wave ballot
    const float* sconf = wsf + OFF_SCONF / 4;
    unsigned long long b1 = __ballot(sconf[tid] > CONF_T);
    unsigned long long b2 = __ballot(sconf[512 + tid] > CONF_T);
    if (lane == 0) { kc[wv] = b1; kc[8 + wv] = b2; }
    __syncthreads();

    if (wv == 0) {
        unsigned long long keep = (lane < 16) ? kc[lane] : 0ULL;
        int l = lane & 15;
        for (int g = 0; g < 16; ++g) {
            unsigned long long cur = __shfl(keep, g);   // replicated chunk g
            const unsigned long long* base = sup + (size_t)g * 64 * 16;
#pragma unroll 16
            for (int ii = 0; ii < 64; ++ii) {
                unsigned long long rl = base[ii * 16 + l];  // my chunk of row i
                unsigned long long rg = base[ii * 16 + g];  // chunk g of row i
                unsigned long long sel = 0ULL - ((cur >> ii) & 1ULL); // keep[i]?
                keep &= ~(rl & sel);
                cur  &= ~(rg & sel);
            }
        }
        if (lane < 16) kc[lane] = keep;
    }
    __syncthreads();

    if (tid < 16) pcs[tid] = (unsigned int)__popcll(kc[tid]);
    __syncthreads();

    if (tid < NDET) {
        int acc = 0, chunk = -1, off = 0;
#pragma unroll
        for (int c = 0; c < 16; ++c) {
            int p = (int)pcs[c];
            if (chunk < 0 && tid < acc + p) { chunk = c; off = tid - acc; }
            acc += p;
        }
        float o0 = 0.f, o1 = 0.f, o2 = 0.f, o3 = 0.f, o4 = 0.f, o5 = 0.f;
        if (chunk >= 0) {   // tid-th surviving box in sorted order
            unsigned long long m = kc[chunk];
            for (int q = 0; q < off; ++q) m &= m - 1ULL;
            int p = chunk * 64 + __builtin_ctzll(m);
            o0 = wsf[OFF_SX1  / 4 + p];
            o1 = wsf[OFF_SY1  / 4 + p];
            o2 = wsf[OFF_SX2  / 4 + p];
            o3 = wsf[OFF_SY2  / 4 + p];
            o4 = wsf[OFF_SCONF / 4 + p];   // kept => conf > CONF_T, row valid
            o5 = wsf[OFF_SCLS / 4 + p];
        }
        out[tid * 6 + 0] = o0; out[tid * 6 + 1] = o1; out[tid * 6 + 2] = o2;
        out[tid * 6 + 3] = o3; out[tid * 6 + 4] = o4; out[tid * 6 + 5] = o5;
    }
}

extern "C" void kernel_launch(void* const* d_in, const int* in_sizes, int n_in,
                              void* d_out, int out_size, void* d_ws, size_t ws_size,
                              hipStream_t stream)
{
    const float* preds = (const float*)d_in[0];   // (32,84,8400); only batch 0 used
    char* ws = (char*)d_ws;
    unsigned int* key  = (unsigned int*)(ws + OFF_KEY);
    float* clsf        = (float*)(ws + OFF_CLS);
    float* conf        = (float*)(ws + OFF_CONF);
    float* wsf         = (float*)ws;
    unsigned long long* sup = (unsigned long long*)(ws + OFF_SUP);
    float* out = (float*)d_out;

    hipLaunchKernelGGL(k_confcls,      dim3(33), dim3(256), 0, stream, preds, key, clsf, conf);
    hipLaunchKernelGGL(k_rank_scatter, dim3(33), dim3(256), 0, stream, preds, key, clsf, conf, wsf);
    hipLaunchKernelGGL(k_supmat,       dim3(64), dim3(256), 0, stream, wsf, sup);
    hipLaunchKernelGGL(k_nms_out,      dim3(1),  dim3(512), 0, stream, wsf, sup, out);
}

// Round 2
// 206.668 us; speedup vs baseline: 1.6321x; 1.6321x over previous
//
#include <hip/hip_runtime.h>
#include <cstdint>
#include <cstddef>

// YOLO NMS for batch 0 of preds (32, 84, 8400) fp32.
// Reference: conf=max(scores), cls=argmax, top_k(1024) by masked conf,
// pairwise IOU on class-offset xyxy boxes, greedy sequential suppression,
// top 300 kept rows -> (300,6) [x1,y1,x2,y2,conf,cls], rest zeros.

#define NA    8400
#define NCLS  80
#define NTOP  1024
#define NDET  300
#define CONF_T 0.25f
#define IOU_T  0.45f
#define MAXWH  7680.0f

#define NSLICE 25          // j-dimension slices for rank computation
#define SLICEW 336         // 25 * 336 = 8400, multiple of 4 for uint4

// ws layout (bytes)
#define OFF_KEY   0        // u32[8400]  sortable key-hi (desc conf)
#define OFF_CLS   33600    // f32[8400]  class as float
#define OFF_CONF  67200    // f32[8400]  masked conf
#define OFF_SCONF 100800   // f32[1024]  sorted (top-1024) conf
#define OFF_SX1   104896
#define OFF_SY1   108992
#define OFF_SX2   113088
#define OFF_SY2   117184
#define OFF_SCLS  121280
#define OFF_SUP   125376   // u64[1024*16] suppression bitmask rows
#define OFF_RANK  256448   // u32[8400]  rank accumulator (atomicAdd)
// total ws usage: 290048 bytes

// swizzled LDS index: breaks the stride-64 (16-way) bank conflict in k_supmat
__device__ __forceinline__ int sw(int j) { return j + (j >> 6); }

// ------- K1: per-anchor conf / argmax / sort key; zero rank buffer -------
__global__ __launch_bounds__(256) void k_confcls(const float* __restrict__ pred,
                                                 unsigned int* __restrict__ key,
                                                 float* __restrict__ clsf,
                                                 float* __restrict__ conf,
                                                 unsigned int* __restrict__ rank)
{
    int a = blockIdx.x * 256 + threadIdx.x;
    if (a >= NA) return;
    const float* s = pred + 4 * NA;
    float best = s[a];          // class 0
    int bc = 0;
#pragma unroll 16
    for (int c = 1; c < NCLS; ++c) {
        float v = s[c * NA + a];
        if (v > best) { best = v; bc = c; }   // strict > == first-occurrence argmax
    }
    float m = (best > CONF_T) ? best : -1.0f; // masked_conf
    unsigned int u = __float_as_uint(m);
    unsigned int mono = u ^ ((u & 0x80000000u) ? 0xFFFFFFFFu : 0x80000000u);
    key[a]  = ~mono;            // ascending key == descending conf
    clsf[a] = (float)bc;
    conf[a] = m;
    rank[a] = 0u;               // zero accumulator for k_rank_partial
}

// ------- K2a: partial rank over one j-slice (exact top_k tie order) -------
__global__ __launch_bounds__(256) void k_rank_partial(const unsigned int* __restrict__ key,
                                                      unsigned int* __restrict__ rank)
{
    __shared__ __align__(16) unsigned int kh[SLICEW];
    int tid = threadIdx.x;
    int s   = blockIdx.y;               // which j-slice
    int jb  = s * SLICEW;
    if (tid < SLICEW - 256 + 256) {}    // (all threads participate below)
    for (int k = tid; k < SLICEW; k += 256) kh[k] = key[jb + k];
    __syncthreads();

    int a = blockIdx.x * 256 + tid;
    if (a >= NA) return;

    unsigned long long myk = (((unsigned long long)key[a]) << 32) | (unsigned int)a;
    unsigned int r = 0;
    const uint4* kv4 = (const uint4*)kh;
#pragma unroll 4
    for (int j4 = 0; j4 < SLICEW / 4; ++j4) {
        uint4 kk = kv4[j4];              // uniform address -> LDS broadcast
        unsigned int j = (unsigned int)jb + (unsigned int)j4 * 4u;
        r += ((((unsigned long long)kk.x) << 32) | (j + 0u)) < myk;
        r += ((((unsigned long long)kk.y) << 32) | (j + 1u)) < myk;
        r += ((((unsigned long long)kk.z) << 32) | (j + 2u)) < myk;
        r += ((((unsigned long long)kk.w) << 32) | (j + 3u)) < myk;
    }
    atomicAdd(&rank[a], r);             // 25 adds per address total: low contention
}

// ---------------- K2b: scatter top-1024 into sorted order ----------------
__global__ __launch_bounds__(256) void k_scatter(const float* __restrict__ pred,
                                                 const unsigned int* __restrict__ rank,
                                                 const float* __restrict__ clsf,
                                                 const float* __restrict__ conf,
                                                 float* __restrict__ wsf)
{
    int a = blockIdx.x * 256 + threadIdx.x;
    if (a >= NA) return;
    unsigned int r = rank[a];
    if (r < NTOP) {
#pragma clang fp contract(off)
        float x = pred[0 * NA + a], y = pred[1 * NA + a];
        float w = pred[2 * NA + a], h = pred[3 * NA + a];
        float hw = w * 0.5f, hh = h * 0.5f;     // xywh -> xyxy, ref op order
        wsf[OFF_SCONF / 4 + r] = conf[a];
        wsf[OFF_SX1  / 4 + r] = x - hw;
        wsf[OFF_SY1  / 4 + r] = y - hh;
        wsf[OFF_SX2  / 4 + r] = x + hw;
        wsf[OFF_SY2  / 4 + r] = y + hh;
        wsf[OFF_SCLS / 4 + r] = clsf[a];
    }
}

// ---------------- K3: 1024x1024 IOU -> suppression bitmask ----------------
__global__ __launch_bounds__(256) void k_supmat(const float* __restrict__ wsf,
                                                unsigned long long* __restrict__ sup)
{
#pragma clang fp contract(off)
    __shared__ float ox1[NTOP + 16], oy1[NTOP + 16];
    __shared__ float ox2[NTOP + 16], oy2[NTOP + 16];
    __shared__ float oar[NTOP + 16];
    int tid = threadIdx.x;
    for (int k = tid; k < NTOP; k += 256) {
        float cls = wsf[OFF_SCLS / 4 + k];
        float off = cls * MAXWH;                 // ref: b + c*MAX_WH
        float x1 = wsf[OFF_SX1 / 4 + k] + off;
        float y1 = wsf[OFF_SY1 / 4 + k] + off;
        float x2 = wsf[OFF_SX2 / 4 + k] + off;
        float y2 = wsf[OFF_SY2 / 4 + k] + off;
        int si = sw(k);
        ox1[si] = x1; oy1[si] = y1; ox2[si] = x2; oy2[si] = y2;
        oar[si] = (x2 - x1) * (y2 - y1);         // area from offset boxes (as ref)
    }
    __syncthreads();

    int gid = blockIdx.x * 256 + tid;            // 64 blocks x 256 = 16384
    int i = gid >> 4;                            // row
    int l = gid & 15;                            // u64 chunk
    int si = sw(i);
    float bx1 = ox1[si], by1 = oy1[si], bx2 = ox2[si], by2 = oy2[si], ba = oar[si];
    unsigned long long bits = 0ULL;
    int j0 = l << 6;
#pragma unroll 4
    for (int jj = 0; jj < 64; ++jj) {
        int j = j0 + jj;
        int sj = sw(j);
        float xx1 = fmaxf(bx1, ox1[sj]);
        float yy1 = fmaxf(by1, oy1[sj]);
        float xx2 = fminf(bx2, ox2[sj]);
        float yy2 = fminf(by2, oy2[sj]);
        float w  = fmaxf(xx2 - xx1, 0.0f);       // clip(rb-lt, 0)
        float hh = fmaxf(yy2 - yy1, 0.0f);
        float inter = w * hh;
        float denom = ba + oar[sj] - inter + 1e-7f;  // ref assoc order
        bool s = (j > i) && ((inter / denom) > IOU_T);
        bits |= ((unsigned long long)s) << jj;
    }
    sup[(size_t)i * 16 + l] = bits;
}

// -------- K4: sequential greedy suppression (1 wave) + emit top-300 --------
__global__ __launch_bounds__(512) void k_nms_out(const float* __restrict__ wsf,
                                                 const unsigned long long* __restrict__ sup,
                                                 float* __restrict__ out)
{
    __shared__ unsigned long long kc[16];
    __shared__ unsigned int pcs[16];
    int tid  = threadIdx.x;
    int lane = tid & 63;
    int wv   = tid >> 6;

    // keep0 = sorted_conf > CONF_T, as 16 u64 chunks via per-wave ballot
    const float* sconf = wsf + OFF_SCONF / 4;
    unsigned long long b1 = __ballot(sconf[tid] > CONF_T);
    unsigned long long b2 = __ballot(sconf[512 + tid] > CONF_T);
    if (lane == 0) { kc[wv] = b1; kc[8 + wv] = b2; }
    __syncthreads();

    if (wv == 0) {
        unsigned long long keep = (lane < 16) ? kc[lane] : 0ULL;
        int l = lane & 15;
        for (int g = 0; g < 16; ++g) {
            unsigned long long cur = __shfl(keep, g);   // replicated chunk g
            const unsigned long long* base = sup + (size_t)g * 64 * 16;
#pragma unroll 16
            for (int ii = 0; ii < 64; ++ii) {
                unsigned long long rl = base[ii * 16 + l];  // my chunk of row i
                unsigned long long rg = base[ii * 16 + g];  // chunk g of row i
                unsigned long long sel = 0ULL - ((cur >> ii) & 1ULL); // keep[i]?
                keep &= ~(rl & sel);
                cur  &= ~(rg & sel);
            }
        }
        if (lane < 16) kc[lane] = keep;
    }
    __syncthreads();

    if (tid < 16) pcs[tid] = (unsigned int)__popcll(kc[tid]);
    __syncthreads();

    if (tid < NDET) {
        int acc = 0, chunk = -1, off = 0;
#pragma unroll
        for (int c = 0; c < 16; ++c) {
            int p = (int)pcs[c];
            if (chunk < 0 && tid < acc + p) { chunk = c; off = tid - acc; }
            acc += p;
        }
        float o0 = 0.f, o1 = 0.f, o2 = 0.f, o3 = 0.f, o4 = 0.f, o5 = 0.f;
        if (chunk >= 0) {   // tid-th surviving box in sorted order
            unsigned long long m = kc[chunk];
            for (int q = 0; q < off; ++q) m &= m - 1ULL;
            int p = chunk * 64 + __builtin_ctzll(m);
            o0 = wsf[OFF_SX1  / 4 + p];
            o1 = wsf[OFF_SY1  / 4 + p];
            o2 = wsf[OFF_SX2  / 4 + p];
            o3 = wsf[OFF_SY2  / 4 + p];
            o4 = wsf[OFF_SCONF / 4 + p];   // kept => conf > CONF_T, row valid
            o5 = wsf[OFF_SCLS / 4 + p];
        }
        out[tid * 6 + 0] = o0; out[tid * 6 + 1] = o1; out[tid * 6 + 2] = o2;
        out[tid * 6 + 3] = o3; out[tid * 6 + 4] = o4; out[tid * 6 + 5] = o5;
    }
}

extern "C" void kernel_launch(void* const* d_in, const int* in_sizes, int n_in,
                              void* d_out, int out_size, void* d_ws, size_t ws_size,
                              hipStream_t stream)
{
    const float* preds = (const float*)d_in[0];   // (32,84,8400); only batch 0 used
    char* ws = (char*)d_ws;
    unsigned int* key  = (unsigned int*)(ws + OFF_KEY);
    float* clsf        = (float*)(ws + OFF_CLS);
    float* conf        = (float*)(ws + OFF_CONF);
    float* wsf         = (float*)ws;
    unsigned long long* sup  = (unsigned long long*)(ws + OFF_SUP);
    unsigned int* rank = (unsigned int*)(ws + OFF_RANK);
    float* out = (float*)d_out;

    hipLaunchKernelGGL(k_confcls,      dim3(33),         dim3(256), 0, stream, preds, key, clsf, conf, rank);
    hipLaunchKernelGGL(k_rank_partial, dim3(33, NSLICE), dim3(256), 0, stream, key, rank);
    hipLaunchKernelGGL(k_scatter,      dim3(33),         dim3(256), 0, stream, preds, rank, clsf, conf, wsf);
    hipLaunchKernelGGL(k_supmat,       dim3(64),         dim3(256), 0, stream, wsf, sup);
    hipLaunchKernelGGL(k_nms_out,      dim3(1),          dim3(512), 0, stream, wsf, sup, out);
}

// Round 3
// 173.252 us; speedup vs baseline: 1.9468x; 1.1929x over previous
//
#include <hip/hip_runtime.h>
#include <cstdint>
#include <cstddef>

// YOLO NMS for batch 0 of preds (32, 84, 8400) fp32.
// Reference: conf=max(scores), cls=argmax, top_k(1024) by masked conf,
// pairwise IOU on class-offset xyxy boxes, greedy sequential suppression,
// top 300 kept rows -> (300,6) [x1,y1,x2,y2,conf,cls], rest zeros.

#define NA    8400
#define NCLS  80
#define NTOP  1024
#define NDET  300
#define CONF_T 0.25f
#define IOU_T  0.45f
#define MAXWH  7680.0f

#define NSLICE 25          // j-dimension slices for rank computation
#define SLICEW 336         // 25 * 336 = 8400, multiple of 4 for uint4

// ws layout (bytes)
#define OFF_KEY   0        // u32[8400]  sortable key-hi (desc conf)
#define OFF_CLS   33600    // f32[8400]  class as float
#define OFF_CONF  67200    // f32[8400]  masked conf
#define OFF_SCONF 100800   // f32[1024]  sorted (top-1024) conf
#define OFF_SX1   104896
#define OFF_SY1   108992
#define OFF_SX2   113088
#define OFF_SY2   117184
#define OFF_SCLS  121280
#define OFF_SUP   125376   // u64[1024*16] suppression bitmask rows
#define OFF_RANK  256448   // u32[8400]  rank accumulator (atomicAdd)
// total ws usage: 290048 bytes

typedef unsigned long long u64;
typedef unsigned int u32;

// swizzled LDS index: breaks the stride-64 (16-way) bank conflict in k_supmat
__device__ __forceinline__ int sw(int j) { return j + (j >> 6); }

__device__ __forceinline__ u32 f2mono(float f) {
    u32 u = __float_as_uint(f);
    return u ^ ((u & 0x80000000u) ? 0xFFFFFFFFu : 0x80000000u);
}
__device__ __forceinline__ float mono2f(u32 m) {
    u32 u = (m & 0x80000000u) ? (m ^ 0x80000000u) : ~m;
    return __uint_as_float(u);
}
// uniform broadcast of lane g's u64 (ignores exec; g < 16 is always active here)
__device__ __forceinline__ u64 rl64(u64 v, int g) {
    u32 lo = (u32)__builtin_amdgcn_readlane((int)(u32)v, g);
    u32 hi = (u32)__builtin_amdgcn_readlane((int)(u32)(v >> 32), g);
    return ((u64)hi << 32) | lo;
}

// ---- K1: conf/argmax over 4 parallel class-slices, LDS combine ----
// grid(33) x 1024 threads: q=tid>>8 handles classes [q*20, q*20+20) for anchor
// a = blockIdx*256 + (tid&255). Packed u64 (mono<<32 | 255-cls): max == larger
// conf, tie -> smaller class (== first-occurrence argmax).
__global__ __launch_bounds__(1024) void k_confcls(const float* __restrict__ pred,
                                                  u32* __restrict__ key,
                                                  float* __restrict__ clsf,
                                                  float* __restrict__ conf,
                                                  u32* __restrict__ rank)
{
    __shared__ u64 pk[4][256];
    int tid = threadIdx.x;
    int q = tid >> 8, t = tid & 255;
    int a = blockIdx.x * 256 + t;
    u64 pv = 0ULL;
    if (a < NA) {
        const float* s = pred + 4 * NA + (size_t)(q * 20) * NA;
        float best = s[a];
        int bc = q * 20;
#pragma unroll
        for (int c = 1; c < 20; ++c) {
            float v = s[(size_t)c * NA + a];
            if (v > best) { best = v; bc = q * 20 + c; }   // strict > == first occurrence
        }
        pv = ((u64)f2mono(best) << 32) | (u32)(255 - bc);
    }
    pk[q][t] = pv;
    __syncthreads();
    if (q == 0 && a < NA) {
        u64 m0 = pk[0][t], m1 = pk[1][t], m2 = pk[2][t], m3 = pk[3][t];
        u64 mm = m0 > m1 ? m0 : m1;
        u64 nn = m2 > m3 ? m2 : m3;
        if (nn > mm) mm = nn;
        float best = mono2f((u32)(mm >> 32));
        int bc = 255 - (int)(mm & 0xFFu);
        float m = (best > CONF_T) ? best : -1.0f;   // masked_conf
        key[a]  = ~f2mono(m);                       // ascending key == descending conf
        clsf[a] = (float)bc;
        conf[a] = m;
        rank[a] = 0u;                               // zero accumulator for k_rank_partial
    }
}

// ------- K2a: partial rank over one j-slice (exact top_k tie order) -------
__global__ __launch_bounds__(256) void k_rank_partial(const u32* __restrict__ key,
                                                      u32* __restrict__ rank)
{
    __shared__ __align__(16) u32 kh[SLICEW];
    int tid = threadIdx.x;
    int s   = blockIdx.y;               // which j-slice
    int jb  = s * SLICEW;
    for (int k = tid; k < SLICEW; k += 256) kh[k] = key[jb + k];
    __syncthreads();

    int a = blockIdx.x * 256 + tid;
    if (a >= NA) return;

    u64 myk = (((u64)key[a]) << 32) | (u32)a;
    u32 r = 0;
    const uint4* kv4 = (const uint4*)kh;
#pragma unroll 4
    for (int j4 = 0; j4 < SLICEW / 4; ++j4) {
        uint4 kk = kv4[j4];              // uniform address -> LDS broadcast
        u32 j = (u32)jb + (u32)j4 * 4u;
        r += ((((u64)kk.x) << 32) | (j + 0u)) < myk;
        r += ((((u64)kk.y) << 32) | (j + 1u)) < myk;
        r += ((((u64)kk.z) << 32) | (j + 2u)) < myk;
        r += ((((u64)kk.w) << 32) | (j + 3u)) < myk;
    }
    atomicAdd(&rank[a], r);             // 25 adds per address total: low contention
}

// ---------------- K2b: scatter top-1024 into sorted order ----------------
__global__ __launch_bounds__(256) void k_scatter(const float* __restrict__ pred,
                                                 const u32* __restrict__ rank,
                                                 const float* __restrict__ clsf,
                                                 const float* __restrict__ conf,
                                                 float* __restrict__ wsf)
{
    int a = blockIdx.x * 256 + threadIdx.x;
    if (a >= NA) return;
    u32 r = rank[a];
    if (r < NTOP) {
#pragma clang fp contract(off)
        float x = pred[0 * NA + a], y = pred[1 * NA + a];
        float w = pred[2 * NA + a], h = pred[3 * NA + a];
        float hw = w * 0.5f, hh = h * 0.5f;     // xywh -> xyxy, ref op order
        wsf[OFF_SCONF / 4 + r] = conf[a];
        wsf[OFF_SX1  / 4 + r] = x - hw;
        wsf[OFF_SY1  / 4 + r] = y - hh;
        wsf[OFF_SX2  / 4 + r] = x + hw;
        wsf[OFF_SY2  / 4 + r] = y + hh;
        wsf[OFF_SCLS / 4 + r] = clsf[a];
    }
}

// ---------------- K3: 1024x1024 IOU -> suppression bitmask ----------------
__global__ __launch_bounds__(256) void k_supmat(const float* __restrict__ wsf,
                                                u64* __restrict__ sup)
{
#pragma clang fp contract(off)
    __shared__ float ox1[NTOP + 16], oy1[NTOP + 16];
    __shared__ float ox2[NTOP + 16], oy2[NTOP + 16];
    __shared__ float oar[NTOP + 16];
    int tid = threadIdx.x;
    for (int k = tid; k < NTOP; k += 256) {
        float cls = wsf[OFF_SCLS / 4 + k];
        float off = cls * MAXWH;                 // ref: b + c*MAX_WH
        float x1 = wsf[OFF_SX1 / 4 + k] + off;
        float y1 = wsf[OFF_SY1 / 4 + k] + off;
        float x2 = wsf[OFF_SX2 / 4 + k] + off;
        float y2 = wsf[OFF_SY2 / 4 + k] + off;
        int si = sw(k);
        ox1[si] = x1; oy1[si] = y1; ox2[si] = x2; oy2[si] = y2;
        oar[si] = (x2 - x1) * (y2 - y1);         // area from offset boxes (as ref)
    }
    __syncthreads();

    int gid = blockIdx.x * 256 + tid;            // 64 blocks x 256 = 16384
    int i = gid >> 4;                            // row
    int l = gid & 15;                            // u64 chunk
    int si = sw(i);
    float bx1 = ox1[si], by1 = oy1[si], bx2 = ox2[si], by2 = oy2[si], ba = oar[si];
    u64 bits = 0ULL;
    int j0 = l << 6;
#pragma unroll 4
    for (int jj = 0; jj < 64; ++jj) {
        int j = j0 + jj;
        int sj = sw(j);
        float xx1 = fmaxf(bx1, ox1[sj]);
        float yy1 = fmaxf(by1, oy1[sj]);
        float xx2 = fminf(bx2, ox2[sj]);
        float yy2 = fminf(by2, oy2[sj]);
        float w  = fmaxf(xx2 - xx1, 0.0f);       // clip(rb-lt, 0)
        float hh = fmaxf(yy2 - yy1, 0.0f);
        float inter = w * hh;
        float denom = ba + oar[sj] - inter + 1e-7f;  // ref assoc order
        bool s = (j > i) && ((inter / denom) > IOU_T);
        bits |= ((u64)s) << jj;
    }
    sup[(size_t)i * 16 + l] = bits;
}

// -------- K4: sequential greedy suppression (1 wave) + emit top-300 --------
// Serial chain is pure scalar ALU: row data prefetched 16 rows/batch into
// double-buffered registers; rg (chunk g of row) extracted via readlane from
// lane g's prefetched rl -- independent of `cur`, so it issues ahead of the
// chain. cur is replicated in all 16 lanes via readlane at group start.
__global__ __launch_bounds__(512) void k_nms_out(const float* __restrict__ wsf,
                                                 const u64* __restrict__ sup,
                                                 float* __restrict__ out)
{
    __shared__ u64 kc[16];
    __shared__ u32 pcs[16];
    int tid  = threadIdx.x;
    int lane = tid & 63;
    int wv   = tid >> 6;

    // keep0 = sorted_conf > CONF_T, as 16 u64 chunks via per-wave ballot
    const float* sconf = wsf + OFF_SCONF / 4;
    u64 b1 = __ballot(sconf[tid] > CONF_T);
    u64 b2 = __ballot(sconf[512 + tid] > CONF_T);
    if (lane == 0) { kc[wv] = b1; kc[8 + wv] = b2; }
    __syncthreads();

    if (wv == 0 && lane < 16) {
        int l = lane;
        u64 keep = kc[l];
        u64 cur = 0ULL;
        u64 A[16], B[16];
#pragma unroll
        for (int k = 0; k < 16; ++k) A[k] = sup[(size_t)k * 16 + l];

        for (int m2 = 0; m2 < 32; ++m2) {
            int m = m2 * 2;
            // prefetch batch m+1
#pragma unroll
            for (int k = 0; k < 16; ++k) B[k] = sup[(size_t)((m + 1) * 16 + k) * 16 + l];
            // process batch m (rows m*16 .. m*16+15)
            {
                int g = m >> 2;
                if ((m & 3) == 0) cur = rl64(keep, g);   // refresh replicated chunk g
                u64 rg[16];
#pragma unroll
                for (int k = 0; k < 16; ++k) rg[k] = rl64(A[k], g);
#pragma unroll
                for (int k = 0; k < 16; ++k) {
                    int ii = ((m & 3) << 4) + k;
                    u64 sel = 0ULL - ((cur >> ii) & 1ULL);   // keep[row]?
                    keep &= ~(A[k] & sel);
                    cur  &= ~(rg[k] & sel);
                }
            }
            // prefetch batch m+2 (skip on last iteration)
            if (m2 < 31) {
#pragma unroll
                for (int k = 0; k < 16; ++k) A[k] = sup[(size_t)((m + 2) * 16 + k) * 16 + l];
            }
            // process batch m+1
            {
                int mb = m + 1;
                int g = mb >> 2;                 // mb odd -> never a group boundary
                u64 rg[16];
#pragma unroll
                for (int k = 0; k < 16; ++k) rg[k] = rl64(B[k], g);
#pragma unroll
                for (int k = 0; k < 16; ++k) {
                    int ii = ((mb & 3) << 4) + k;
                    u64 sel = 0ULL - ((cur >> ii) & 1ULL);
                    keep &= ~(B[k] & sel);
                    cur  &= ~(rg[k] & sel);
                }
            }
        }
        kc[l] = keep;
    }
    __syncthreads();

    if (tid < 16) pcs[tid] = (u32)__popcll(kc[tid]);
    __syncthreads();

    if (tid < NDET) {
        int acc = 0, chunk = -1, off = 0;
#pragma unroll
        for (int c = 0; c < 16; ++c) {
            int p = (int)pcs[c];
            if (chunk < 0 && tid < acc + p) { chunk = c; off = tid - acc; }
            acc += p;
        }
        float o0 = 0.f, o1 = 0.f, o2 = 0.f, o3 = 0.f, o4 = 0.f, o5 = 0.f;
        if (chunk >= 0) {   // tid-th surviving box in sorted order
            u64 mk = kc[chunk];
            for (int q = 0; q < off; ++q) mk &= mk - 1ULL;
            int p = chunk * 64 + __builtin_ctzll(mk);
            o0 = wsf[OFF_SX1  / 4 + p];
            o1 = wsf[OFF_SY1  / 4 + p];
            o2 = wsf[OFF_SX2  / 4 + p];
            o3 = wsf[OFF_SY2  / 4 + p];
            o4 = wsf[OFF_SCONF / 4 + p];   // kept => conf > CONF_T, row valid
            o5 = wsf[OFF_SCLS / 4 + p];
        }
        out[tid * 6 + 0] = o0; out[tid * 6 + 1] = o1; out[tid * 6 + 2] = o2;
        out[tid * 6 + 3] = o3; out[tid * 6 + 4] = o4; out[tid * 6 + 5] = o5;
    }
}

extern "C" void kernel_launch(void* const* d_in, const int* in_sizes, int n_in,
                              void* d_out, int out_size, void* d_ws, size_t ws_size,
                              hipStream_t stream)
{
    const float* preds = (const float*)d_in[0];   // (32,84,8400); only batch 0 used
    char* ws = (char*)d_ws;
    u32* key    = (u32*)(ws + OFF_KEY);
    float* clsf = (float*)(ws + OFF_CLS);
    float* conf = (float*)(ws + OFF_CONF);
    float* wsf  = (float*)ws;
    u64* sup    = (u64*)(ws + OFF_SUP);
    u32* rank   = (u32*)(ws + OFF_RANK);
    float* out  = (float*)d_out;

    hipLaunchKernelGGL(k_confcls,      dim3(33),         dim3(1024), 0, stream, preds, key, clsf, conf, rank);
    hipLaunchKernelGGL(k_rank_partial, dim3(33, NSLICE), dim3(256),  0, stream, key, rank);
    hipLaunchKernelGGL(k_scatter,      dim3(33),         dim3(256),  0, stream, preds, rank, clsf, conf, wsf);
    hipLaunchKernelGGL(k_supmat,       dim3(64),         dim3(256),  0, stream, wsf, sup);
    hipLaunchKernelGGL(k_nms_out,      dim3(1),          dim3(512),  0, stream, wsf, sup, out);
}